// Round 5
// baseline (720.694 us; speedup 1.0000x reference)
//
#include <hip/hip_runtime.h>
#include <hip/hip_bf16.h>
#include <math.h>

typedef __hip_bfloat16 bf16;

#define FEAT 128
#define NRBF 20
#define CUTOFF_F 5.0f
#define KSCALE 0.62831853071795864769f  // pi / 5

__device__ __forceinline__ float b2f(bf16 x) { return __bfloat162float(x); }
__device__ __forceinline__ bf16 f2b(float x) { return __float2bfloat16(x); }

template<int F32>
__device__ __forceinline__ float LD(const void* p, size_t i) {
    if (F32) return ((const float*)p)[i];
    return b2f(((const bf16*)p)[i]);
}
template<int F32>
__device__ __forceinline__ void ST(void* p, size_t i, float v) {
    if (F32) ((float*)p)[i] = v;
    else ((bf16*)p)[i] = f2b(v);
}

__device__ __forceinline__ int get_dst(const int* nb, int e, int is64) {
    return is64 ? nb[4 * e] : nb[2 * e];
}
__device__ __forceinline__ int get_src(const int* nb, int e, int is64) {
    return is64 ? nb[4 * e + 2] : nb[2 * e + 1];
}
__device__ __forceinline__ int clampi(int v, int n) {
    return v < 0 ? 0 : (v >= n ? n - 1 : v);
}

// ---------- init: zero counts + sniff dtypes ----------
__global__ void init_kernel(const void* __restrict__ s_ptr, const int* __restrict__ nbrs32,
                            int nE, int* __restrict__ flags, int* __restrict__ counts, int nN) {
    int t = blockIdx.x * blockDim.x + threadIdx.x;
    if (t < nN) counts[t] = 0;
    if (t == 0) {
        const unsigned* u = (const unsigned*)s_ptr;
        int hits = 0;
        for (int i = 0; i < 64; ++i) {
            unsigned ef = (u[i] >> 7) & 0xFF;
            hits += (ef >= 110 && ef <= 135) ? 1 : 0;
        }
        flags[0] = (hits < 32) ? 1 : 0;
        int lim = 2 * nE; if (lim > 128) lim = 128;
        int allz = 1;
        for (int i = 1; i < lim; i += 2) allz &= (nbrs32[i] == 0);
        flags[1] = allz;
    }
}

// ---------- CSR build ----------
__global__ void hist_kernel(const int* __restrict__ nbrs, const int* __restrict__ flags,
                            int* __restrict__ counts, int nE, int nN) {
    int e = blockIdx.x * blockDim.x + threadIdx.x;
    if (e < nE) {
        int d = clampi(get_dst(nbrs, e, flags[1]), nN);
        atomicAdd(&counts[d], 1);
    }
}

__global__ __launch_bounds__(1024) void scan_kernel(const int* __restrict__ counts,
        int* __restrict__ offsets, int* __restrict__ cursor, int nN) {
    __shared__ int part[1024];
    const int t = threadIdx.x;
    const int chunk = (nN + 1023) / 1024;
    const int base = t * chunk;
    int local[32];
    int sum = 0;
    for (int c = 0; c < chunk && c < 32; ++c) {
        int idx = base + c;
        int v = (idx < nN) ? counts[idx] : 0;
        local[c] = v;
        sum += v;
    }
    part[t] = sum;
    __syncthreads();
    for (int off = 1; off < 1024; off <<= 1) {
        int add = (t >= off) ? part[t - off] : 0;
        __syncthreads();
        part[t] += add;
        __syncthreads();
    }
    int run = part[t] - sum;
    for (int c = 0; c < chunk && c < 32; ++c) {
        int idx = base + c;
        if (idx < nN) { offsets[idx] = run; cursor[idx] = run; run += local[c]; }
    }
    if (t == 1023) offsets[nN] = part[1023];
}

// ---------- fused scatter + per-edge g-record precompute ----------
// record: g[0..19] (= sin(k x)*invd*env), ux, uy, uz, env
template<int F32, int GM>   // GM: 2 = f32 record, 1 = bf16 record, 0 = scatter only
__global__ __launch_bounds__(256) void pre_scatter_kernel(
        const void* __restrict__ r_ij, const int* __restrict__ nbrs,
        const int* __restrict__ flags, int* __restrict__ cursor,
        int* __restrict__ edge_ids, void* __restrict__ gbuf, int nE, int nN) {
    if (flags[0] != F32) return;
    int e = blockIdx.x * blockDim.x + threadIdx.x;
    if (e >= nE) return;

    // scatter into CSR
    int d = clampi(get_dst(nbrs, e, flags[1]), nN);
    int pos = atomicAdd(&cursor[d], 1);
    if (pos >= 0 && pos < nE) edge_ids[pos] = e;

    if (GM == 0) return;

    const float rx = LD<F32>(r_ij, (size_t)3 * e + 0);
    const float ry = LD<F32>(r_ij, (size_t)3 * e + 1);
    const float rz = LD<F32>(r_ij, (size_t)3 * e + 2);
    const float d2   = rx * rx + ry * ry + rz * rz + 3e-15f;
    const float invd = rsqrtf(d2);
    const float dd   = d2 * invd;
    const float x  = dd * KSCALE;
    const float s1 = F32 ? sinf(x) : __sinf(x);
    const float c1 = F32 ? cosf(x) : __cosf(x);
    const float env = (dd < CUTOFF_F) ? (0.5f * (c1 + 1.0f)) : 0.0f;
    const float scale = invd * env;
    float rec[24];
    const float tc = 2.0f * c1;
    float skm2 = 0.f, skm1 = s1;
    rec[0] = s1 * scale;
    #pragma unroll
    for (int k = 1; k < NRBF; ++k) {
        const float sk = fmaf(tc, skm1, -skm2);
        rec[k] = sk * scale;
        skm2 = skm1; skm1 = sk;
    }
    rec[20] = rx * invd; rec[21] = ry * invd; rec[22] = rz * invd; rec[23] = env;
    if (GM == 2) {
        float* dst = (float*)gbuf + (size_t)24 * e;
        #pragma unroll
        for (int i = 0; i < 24; ++i) dst[i] = rec[i];
    } else {
        bf16* dst = (bf16*)gbuf + (size_t)24 * e;
        #pragma unroll
        for (int i = 0; i < 24; ++i) dst[i] = f2b(rec[i]);
    }
}

// ---------- fused node MLP: phi = silu(s@W1+b1)@W2 + b2 (phi stored bf16) ----------
template<int F32>
__device__ void gemm_body(const void* __restrict__ s_j, const void* __restrict__ W1,
                          const void* __restrict__ b1, const void* __restrict__ W2,
                          const void* __restrict__ b2v, bf16* __restrict__ phi, int nN) {
    __shared__ float sl[8][FEAT];
    __shared__ float hl[8][FEAT];
    const int t = threadIdx.x;
    const int n0 = blockIdx.x * 8;
    for (int idx = t; idx < 8 * FEAT; idx += 384) {
        int n = idx >> 7, k = idx & 127;
        int row = n0 + n;
        sl[n][k] = (row < nN) ? LD<F32>(s_j, (size_t)row * FEAT + k) : 0.f;
    }
    __syncthreads();
    for (int idx = t; idx < 8 * FEAT; idx += 384) {
        int n = idx >> 7, f = idx & 127;
        float a = 0.f;
        #pragma unroll 4
        for (int k = 0; k < FEAT; ++k) a = fmaf(sl[n][k], LD<F32>(W1, (size_t)k * FEAT + f), a);
        a += LD<F32>(b1, f);
        float sg = F32 ? (1.0f / (1.0f + expf(-a))) : (1.0f / (1.0f + __expf(-a)));
        hl[n][f] = a * sg;
    }
    __syncthreads();
    float acc[8] = {};
    #pragma unroll 4
    for (int k = 0; k < FEAT; ++k) {
        const float w = LD<F32>(W2, (size_t)k * 384 + t);
        #pragma unroll
        for (int n = 0; n < 8; ++n) acc[n] = fmaf(hl[n][k], w, acc[n]);
    }
    const float bb = LD<F32>(b2v, t);
    #pragma unroll
    for (int n = 0; n < 8; ++n) {
        int row = n0 + n;
        if (row < nN) phi[(size_t)row * 384 + t] = f2b(acc[n] + bb);
    }
}

__global__ __launch_bounds__(384) void gemm_node_kernel(const void* s_j, const void* W1,
        const void* b1, const void* W2, const void* b2v, bf16* phi,
        const int* __restrict__ flags, int nN) {
    if (flags[0]) gemm_body<1>(s_j, W1, b1, W2, b2v, phi, nN);
    else          gemm_body<0>(s_j, W1, b1, W2, b2v, phi, nN);
}

// ---------- fused per-node message + reduce ----------
template<int F32, int GM>
__global__ __launch_bounds__(128, 2) void msg_kernel(
        const int* __restrict__ nbrs, const void* __restrict__ r_ij,
        const void* __restrict__ v_j, const void* __restrict__ Wd,
        const void* __restrict__ bd, const bf16* __restrict__ phi,
        const void* __restrict__ gbuf, const int* __restrict__ flags,
        const int* __restrict__ offsets, const int* __restrict__ edge_ids,
        void* __restrict__ out, int nE, int nN) {
    if (flags[0] != F32) return;
    const int i = blockIdx.x;
    const int f = threadIdx.x;
    const int lane = f & 63;
    const int is64 = flags[1];

    // Wd columns for channels f, f+128, f+256 — pinned in VGPRs (asm barrier
    // prevents the compiler from re-materializing these loads in the edge loop).
    float wd0[NRBF], wd1[NRBF], wd2[NRBF];
    #pragma unroll
    for (int k = 0; k < NRBF; ++k) {
        wd0[k] = LD<F32>(Wd, (size_t)k * 384 + f);
        wd1[k] = LD<F32>(Wd, (size_t)k * 384 + FEAT + f);
        wd2[k] = LD<F32>(Wd, (size_t)k * 384 + 2 * FEAT + f);
    }
    #pragma unroll
    for (int k = 0; k < NRBF; ++k) {
        asm volatile("" : "+v"(wd0[k]), "+v"(wd1[k]), "+v"(wd2[k]));
    }
    const float bd0 = LD<F32>(bd, f);
    const float bd1 = LD<F32>(bd, FEAT + f);
    const float bd2 = LD<F32>(bd, 2 * FEAT + f);

    float ds = 0.f, dv0 = 0.f, dv1 = 0.f, dv2 = 0.f;

    int start = offsets[i];
    int end   = offsets[i + 1];
    if (start < 0) start = 0;
    if (end > nE) end = nE;
    const int cnt = end - start;

    for (int base = 0; base < cnt; base += 64) {
        const int m = (cnt - base < 64) ? (cnt - base) : 64;
        // cooperative batch load of (e, j): one coalesced pass per wave
        int eL = 0, jL = 0;
        if (lane < m) {
            eL = clampi(edge_ids[start + base + lane], nE);
            jL = clampi(get_src(nbrs, eL, is64), nN);
        }
        #pragma unroll 2
        for (int q = 0; q < m; ++q) {
            const int e = __shfl(eL, q);
            const int j = __shfl(jL, q);

            float gk[24];
            if (GM == 2) {
                const float4* g4 = (const float4*)((const float*)gbuf + (size_t)24 * e);
                #pragma unroll
                for (int c = 0; c < 6; ++c) {
                    float4 v = g4[c];
                    gk[4 * c + 0] = v.x; gk[4 * c + 1] = v.y;
                    gk[4 * c + 2] = v.z; gk[4 * c + 3] = v.w;
                }
            } else if (GM == 1) {
                const bf16* g = (const bf16*)gbuf + (size_t)24 * e;
                #pragma unroll
                for (int c = 0; c < 24; ++c) gk[c] = b2f(g[c]);
            } else {
                const float rx = LD<F32>(r_ij, (size_t)3 * e + 0);
                const float ry = LD<F32>(r_ij, (size_t)3 * e + 1);
                const float rz = LD<F32>(r_ij, (size_t)3 * e + 2);
                const float d2   = rx * rx + ry * ry + rz * rz + 3e-15f;
                const float invd = rsqrtf(d2);
                const float dd   = d2 * invd;
                const float x  = dd * KSCALE;
                const float s1 = F32 ? sinf(x) : __sinf(x);
                const float c1 = F32 ? cosf(x) : __cosf(x);
                const float env = (dd < CUTOFF_F) ? (0.5f * (c1 + 1.0f)) : 0.0f;
                const float scale = invd * env;
                const float tc = 2.0f * c1;
                float skm2 = 0.f, skm1 = s1;
                gk[0] = s1 * scale;
                #pragma unroll
                for (int k = 1; k < NRBF; ++k) {
                    const float sk = fmaf(tc, skm1, -skm2);
                    gk[k] = sk * scale;
                    skm2 = skm1; skm1 = sk;
                }
                gk[20] = rx * invd; gk[21] = ry * invd; gk[22] = rz * invd; gk[23] = env;
            }

            // gathers — addresses depend only on j (known at batch start)
            const size_t pb = (size_t)j * 384;
            const float p0 = b2f(phi[pb + f]);
            const float p1 = b2f(phi[pb + FEAT + f]);
            const float p2 = b2f(phi[pb + 2 * FEAT + f]);
            const size_t vb = ((size_t)j * FEAT + f) * 3;
            const float vx = LD<F32>(v_j, vb + 0);
            const float vy = LD<F32>(v_j, vb + 1);
            const float vz = LD<F32>(v_j, vb + 2);

            float t0 = gk[0] * wd0[0], t1 = gk[0] * wd1[0], t2 = gk[0] * wd2[0];
            #pragma unroll
            for (int k = 1; k < NRBF; ++k) {
                t0 = fmaf(gk[k], wd0[k], t0);
                t1 = fmaf(gk[k], wd1[k], t1);
                t2 = fmaf(gk[k], wd2[k], t2);
            }
            const float env = gk[23];
            const float w0 = fmaf(bd0, env, t0);
            const float w1 = fmaf(bd1, env, t1);
            const float w2 = fmaf(bd2, env, t2);

            const float i0 = w0 * p0;
            const float i1 = w1 * p1;
            const float i2 = w2 * p2;
            ds += i1;
            dv0 = fmaf(i2, gk[20], fmaf(i0, vx, dv0));
            dv1 = fmaf(i2, gk[21], fmaf(i0, vy, dv1));
            dv2 = fmaf(i2, gk[22], fmaf(i0, vz, dv2));
        }
    }

    ST<F32>(out, (size_t)i * FEAT + f, ds);
    const size_t ob = (size_t)nN * FEAT + ((size_t)i * FEAT + f) * 3;
    ST<F32>(out, ob + 0, dv0);
    ST<F32>(out, ob + 1, dv1);
    ST<F32>(out, ob + 2, dv2);
}

extern "C" void kernel_launch(void* const* d_in, const int* in_sizes, int n_in,
                              void* d_out, int out_size, void* d_ws, size_t ws_size,
                              hipStream_t stream) {
    const void* s_j  = d_in[0];
    const void* v_j  = d_in[1];
    const void* r_ij = d_in[2];
    const int*  nbrs = (const int*)d_in[3];
    const void* W1   = d_in[4];
    const void* b1   = d_in[5];
    const void* W2   = d_in[6];
    const void* b2   = d_in[7];
    const void* Wd   = d_in[8];
    const void* bd   = d_in[9];

    const int nN = out_size / (4 * FEAT);   // 20000
    const int nE = in_sizes[2] / 3;         // 640000

    // workspace: flags | counts | offsets | cursor | edge_ids | gbuf | phi(bf16)
    char* ws = (char*)d_ws;
    size_t off = 0;
    int* flags = (int*)(ws + off);    off += 256;
    int* counts = (int*)(ws + off);   off += ((size_t)nN * 4 + 255) & ~(size_t)255;
    int* offsets = (int*)(ws + off);  off += (((size_t)nN + 1) * 4 + 255) & ~(size_t)255;
    int* cursor = (int*)(ws + off);   off += ((size_t)nN * 4 + 255) & ~(size_t)255;
    int* edge_ids = (int*)(ws + off); off += ((size_t)nE * 4 + 255) & ~(size_t)255;

    const size_t phi_bytes = (size_t)nN * 384 * sizeof(bf16);
    const size_t g32_bytes = (size_t)nE * 24 * 4;
    const size_t g16_bytes = (size_t)nE * 24 * 2;
    int GM;
    size_t g_bytes;
    if (ws_size >= off + g32_bytes + phi_bytes)      { GM = 2; g_bytes = g32_bytes; }
    else if (ws_size >= off + g16_bytes + phi_bytes) { GM = 1; g_bytes = g16_bytes; }
    else                                             { GM = 0; g_bytes = 0; }
    void* gbuf = (void*)(ws + off);   off += (g_bytes + 255) & ~(size_t)255;
    bf16* phi = (bf16*)(ws + off);

    init_kernel<<<(nN + 255) / 256, 256, 0, stream>>>(s_j, nbrs, nE, flags, counts, nN);
    hist_kernel<<<(nE + 255) / 256, 256, 0, stream>>>(nbrs, flags, counts, nE, nN);
    scan_kernel<<<1, 1024, 0, stream>>>(counts, offsets, cursor, nN);

    const int preg = (nE + 255) / 256;
    if (GM == 2) {
        pre_scatter_kernel<0, 2><<<preg, 256, 0, stream>>>(r_ij, nbrs, flags, cursor, edge_ids, gbuf, nE, nN);
        pre_scatter_kernel<1, 2><<<preg, 256, 0, stream>>>(r_ij, nbrs, flags, cursor, edge_ids, gbuf, nE, nN);
    } else if (GM == 1) {
        pre_scatter_kernel<0, 1><<<preg, 256, 0, stream>>>(r_ij, nbrs, flags, cursor, edge_ids, gbuf, nE, nN);
        pre_scatter_kernel<1, 1><<<preg, 256, 0, stream>>>(r_ij, nbrs, flags, cursor, edge_ids, gbuf, nE, nN);
    } else {
        pre_scatter_kernel<0, 0><<<preg, 256, 0, stream>>>(r_ij, nbrs, flags, cursor, edge_ids, gbuf, nE, nN);
        pre_scatter_kernel<1, 0><<<preg, 256, 0, stream>>>(r_ij, nbrs, flags, cursor, edge_ids, gbuf, nE, nN);
    }

    gemm_node_kernel<<<(nN + 7) / 8, 384, 0, stream>>>(s_j, W1, b1, W2, b2, phi, flags, nN);

    if (GM == 2) {
        msg_kernel<0, 2><<<nN, 128, 0, stream>>>(nbrs, r_ij, v_j, Wd, bd, phi, gbuf, flags, offsets, edge_ids, d_out, nE, nN);
        msg_kernel<1, 2><<<nN, 128, 0, stream>>>(nbrs, r_ij, v_j, Wd, bd, phi, gbuf, flags, offsets, edge_ids, d_out, nE, nN);
    } else if (GM == 1) {
        msg_kernel<0, 1><<<nN, 128, 0, stream>>>(nbrs, r_ij, v_j, Wd, bd, phi, gbuf, flags, offsets, edge_ids, d_out, nE, nN);
        msg_kernel<1, 1><<<nN, 128, 0, stream>>>(nbrs, r_ij, v_j, Wd, bd, phi, gbuf, flags, offsets, edge_ids, d_out, nE, nN);
    } else {
        msg_kernel<0, 0><<<nN, 128, 0, stream>>>(nbrs, r_ij, v_j, Wd, bd, phi, gbuf, flags, offsets, edge_ids, d_out, nE, nN);
        msg_kernel<1, 0><<<nN, 128, 0, stream>>>(nbrs, r_ij, v_j, Wd, bd, phi, gbuf, flags, offsets, edge_ids, d_out, nE, nN);
    }
}

// Round 6
// 534.556 us; speedup vs baseline: 1.3482x; 1.3482x over previous
//
#include <hip/hip_runtime.h>
#include <hip/hip_bf16.h>
#include <math.h>

typedef __hip_bfloat16 bf16;

#define FEAT 128
#define NRBF 20
#define CUTOFF_F 5.0f
#define KSCALE 0.62831853071795864769f  // pi / 5

__device__ __forceinline__ float b2f(bf16 x) { return __bfloat162float(x); }
__device__ __forceinline__ bf16 f2b(float x) { return __float2bfloat16(x); }

template<int F32>
__device__ __forceinline__ float LD(const void* p, size_t i) {
    if (F32) return ((const float*)p)[i];
    return b2f(((const bf16*)p)[i]);
}
template<int F32>
__device__ __forceinline__ void ST(void* p, size_t i, float v) {
    if (F32) ((float*)p)[i] = v;
    else ((bf16*)p)[i] = f2b(v);
}

__device__ __forceinline__ int get_dst(const int* nb, int e, int is64) {
    return is64 ? nb[4 * e] : nb[2 * e];
}
__device__ __forceinline__ int get_src(const int* nb, int e, int is64) {
    return is64 ? nb[4 * e + 2] : nb[2 * e + 1];
}
__device__ __forceinline__ int clampi(int v, int n) {
    return v < 0 ? 0 : (v >= n ? n - 1 : v);
}

// ---------- init: zero counts + sniff dtypes ----------
__global__ void init_kernel(const void* __restrict__ s_ptr, const int* __restrict__ nbrs32,
                            int nE, int* __restrict__ flags, int* __restrict__ counts, int nN) {
    int t = blockIdx.x * blockDim.x + threadIdx.x;
    if (t < nN) counts[t] = 0;
    if (t == 0) {
        const unsigned* u = (const unsigned*)s_ptr;
        int hits = 0;
        for (int i = 0; i < 64; ++i) {
            unsigned ef = (u[i] >> 7) & 0xFF;
            hits += (ef >= 110 && ef <= 135) ? 1 : 0;
        }
        flags[0] = (hits < 32) ? 1 : 0;   // 1 => f32 inputs
        int lim = 2 * nE; if (lim > 128) lim = 128;
        int allz = 1;
        for (int i = 1; i < lim; i += 2) allz &= (nbrs32[i] == 0);
        flags[1] = allz;                   // 1 => int64 nbrs
    }
}

// ---------- CSR build ----------
__global__ void hist_kernel(const int* __restrict__ nbrs, const int* __restrict__ flags,
                            int* __restrict__ counts, int nE, int nN) {
    int e = blockIdx.x * blockDim.x + threadIdx.x;
    if (e < nE) {
        int d = clampi(get_dst(nbrs, e, flags[1]), nN);
        atomicAdd(&counts[d], 1);
    }
}

__global__ __launch_bounds__(1024) void scan_kernel(const int* __restrict__ counts,
        int* __restrict__ offsets, int* __restrict__ cursor, int nN) {
    __shared__ int part[1024];
    const int t = threadIdx.x;
    const int chunk = (nN + 1023) / 1024;
    const int base = t * chunk;
    int local[32];
    int sum = 0;
    for (int c = 0; c < chunk && c < 32; ++c) {
        int idx = base + c;
        int v = (idx < nN) ? counts[idx] : 0;
        local[c] = v;
        sum += v;
    }
    part[t] = sum;
    __syncthreads();
    for (int off = 1; off < 1024; off <<= 1) {
        int add = (t >= off) ? part[t - off] : 0;
        __syncthreads();
        part[t] += add;
        __syncthreads();
    }
    int run = part[t] - sum;
    for (int c = 0; c < chunk && c < 32; ++c) {
        int idx = base + c;
        if (idx < nN) { offsets[idx] = run; cursor[idx] = run; run += local[c]; }
    }
    if (t == 1023) offsets[nN] = part[1023];
}

// ---------- prep: WdT[c][0..19] = Wd[k][c] (f32), WdT[c][20] = bd[c]; rows padded to 24 ----------
__global__ __launch_bounds__(384) void prep_kernel(const void* __restrict__ Wd,
        const void* __restrict__ bd, float* __restrict__ WdT, const int* __restrict__ flags) {
    const int c = threadIdx.x;
    const int F32 = flags[0];
    if (F32) {
        for (int k = 0; k < NRBF; ++k) WdT[c * 24 + k] = ((const float*)Wd)[k * 384 + c];
        WdT[c * 24 + 20] = ((const float*)bd)[c];
    } else {
        for (int k = 0; k < NRBF; ++k) WdT[c * 24 + k] = b2f(((const bf16*)Wd)[k * 384 + c]);
        WdT[c * 24 + 20] = b2f(((const bf16*)bd)[c]);
    }
    WdT[c * 24 + 21] = 0.f; WdT[c * 24 + 22] = 0.f; WdT[c * 24 + 23] = 0.f;
}

// ---------- scatter + per-position side records ----------
// writes: src_ids[pos]=j, u_env[pos]={ux,uy,uz,env}, and
//   modeA: pos_of_e[e]=pos      modeB: gbuf[pos*20+k]=gk[k]
template<int F32, int MODEA>
__device__ void pre_scatter_body(const void* __restrict__ r_ij, const int* __restrict__ nbrs,
        int is64, int* __restrict__ cursor, int* __restrict__ src_ids,
        float4* __restrict__ u_env, int* __restrict__ pos_of_e, float* __restrict__ gbuf,
        int e, int nE, int nN) {
    const int d = clampi(get_dst(nbrs, e, is64), nN);
    const int j = clampi(get_src(nbrs, e, is64), nN);
    int pos = atomicAdd(&cursor[d], 1);
    pos = clampi(pos, nE);
    src_ids[pos] = j;

    const float rx = LD<F32>(r_ij, (size_t)3 * e + 0);
    const float ry = LD<F32>(r_ij, (size_t)3 * e + 1);
    const float rz = LD<F32>(r_ij, (size_t)3 * e + 2);
    const float d2   = rx * rx + ry * ry + rz * rz + 3e-15f;
    const float invd = rsqrtf(d2);
    const float dd   = d2 * invd;
    const float x  = dd * KSCALE;
    const float c1 = F32 ? cosf(x) : __cosf(x);
    const float env = (dd < CUTOFF_F) ? (0.5f * (c1 + 1.0f)) : 0.0f;
    u_env[pos] = make_float4(rx * invd, ry * invd, rz * invd, env);

    if (MODEA) {
        pos_of_e[e] = pos;
    } else {
        const float s1 = F32 ? sinf(x) : __sinf(x);
        const float scale = invd * env;
        const float tc = 2.0f * c1;
        float skm2 = 0.f, skm1 = s1;
        float* g = gbuf + (size_t)pos * NRBF;
        g[0] = s1 * scale;
        #pragma unroll
        for (int k = 1; k < NRBF; ++k) {
            const float sk = fmaf(tc, skm1, -skm2);
            g[k] = sk * scale;
            skm2 = skm1; skm1 = sk;
        }
    }
}

__global__ __launch_bounds__(256) void pre_scatter_kernel(const void* r_ij, const int* nbrs,
        const int* __restrict__ flags, int* cursor, int* src_ids, float4* u_env,
        int* pos_of_e, float* gbuf, int nE, int nN, int modeA) {
    int e = blockIdx.x * blockDim.x + threadIdx.x;
    if (e >= nE) return;
    const int F32 = flags[0], is64 = flags[1];
    if (modeA) {
        if (F32) pre_scatter_body<1,1>(r_ij, nbrs, is64, cursor, src_ids, u_env, pos_of_e, gbuf, e, nE, nN);
        else     pre_scatter_body<0,1>(r_ij, nbrs, is64, cursor, src_ids, u_env, pos_of_e, gbuf, e, nE, nN);
    } else {
        if (F32) pre_scatter_body<1,0>(r_ij, nbrs, is64, cursor, src_ids, u_env, pos_of_e, gbuf, e, nE, nN);
        else     pre_scatter_body<0,0>(r_ij, nbrs, is64, cursor, src_ids, u_env, pos_of_e, gbuf, e, nE, nN);
    }
}

// ---------- fused node MLP: phi = silu(s@W1+b1)@W2 + b2 (phi bf16) ----------
template<int F32>
__device__ void gemm_body(const void* __restrict__ s_j, const void* __restrict__ W1,
                          const void* __restrict__ b1, const void* __restrict__ W2,
                          const void* __restrict__ b2v, bf16* __restrict__ phi, int nN) {
    __shared__ float sl[8][FEAT];
    __shared__ float hl[8][FEAT];
    const int t = threadIdx.x;
    const int n0 = blockIdx.x * 8;
    for (int idx = t; idx < 8 * FEAT; idx += 384) {
        int n = idx >> 7, k = idx & 127;
        int row = n0 + n;
        sl[n][k] = (row < nN) ? LD<F32>(s_j, (size_t)row * FEAT + k) : 0.f;
    }
    __syncthreads();
    for (int idx = t; idx < 8 * FEAT; idx += 384) {
        int n = idx >> 7, f = idx & 127;
        float a = 0.f;
        #pragma unroll 4
        for (int k = 0; k < FEAT; ++k) a = fmaf(sl[n][k], LD<F32>(W1, (size_t)k * FEAT + f), a);
        a += LD<F32>(b1, f);
        float sg = F32 ? (1.0f / (1.0f + expf(-a))) : (1.0f / (1.0f + __expf(-a)));
        hl[n][f] = a * sg;
    }
    __syncthreads();
    float acc[8] = {};
    #pragma unroll 4
    for (int k = 0; k < FEAT; ++k) {
        const float w = LD<F32>(W2, (size_t)k * 384 + t);
        #pragma unroll
        for (int n = 0; n < 8; ++n) acc[n] = fmaf(hl[n][k], w, acc[n]);
    }
    const float bb = LD<F32>(b2v, t);
    #pragma unroll
    for (int n = 0; n < 8; ++n) {
        int row = n0 + n;
        if (row < nN) phi[(size_t)row * 384 + t] = f2b(acc[n] + bb);
    }
}

__global__ __launch_bounds__(384) void gemm_node_kernel(const void* s_j, const void* W1,
        const void* b1, const void* W2, const void* b2v, bf16* phi,
        const int* __restrict__ flags, int nN) {
    if (flags[0]) gemm_body<1>(s_j, W1, b1, W2, b2v, phi, nN);
    else          gemm_body<0>(s_j, W1, b1, W2, b2v, phi, nN);
}

// ---------- mode A: per-edge w_s GEMM (lane=edge, channels via uniform s_loads) ----------
template<int F32>
__device__ void pre_ws_body(const void* __restrict__ r_ij, const float* __restrict__ WdT,
        const int* __restrict__ pos_of_e, bf16* __restrict__ ws_w, int e) {
    const float rx = LD<F32>(r_ij, (size_t)3 * e + 0);
    const float ry = LD<F32>(r_ij, (size_t)3 * e + 1);
    const float rz = LD<F32>(r_ij, (size_t)3 * e + 2);
    const float d2   = rx * rx + ry * ry + rz * rz + 3e-15f;
    const float invd = rsqrtf(d2);
    const float dd   = d2 * invd;
    const float x  = dd * KSCALE;
    const float s1 = F32 ? sinf(x) : __sinf(x);
    const float c1 = F32 ? cosf(x) : __cosf(x);
    const float env = (dd < CUTOFF_F) ? (0.5f * (c1 + 1.0f)) : 0.0f;
    const float scale = invd * env;
    float gk[NRBF];
    const float tc = 2.0f * c1;
    float skm2 = 0.f, skm1 = s1;
    gk[0] = s1 * scale;
    #pragma unroll
    for (int k = 1; k < NRBF; ++k) {
        const float sk = fmaf(tc, skm1, -skm2);
        gk[k] = sk * scale;
        skm2 = skm1; skm1 = sk;
    }
    const int pos = pos_of_e[e];
    bf16* dst = ws_w + (size_t)pos * 384;
    for (int c0 = 0; c0 < 384; c0 += 4) {
        float r[4];
        #pragma unroll
        for (int u = 0; u < 4; ++u) {
            const float* w = WdT + (size_t)(c0 + u) * 24;  // uniform address -> s_load
            float acc = w[20] * env;                        // bd*env
            #pragma unroll
            for (int k = 0; k < NRBF; ++k) acc = fmaf(gk[k], w[k], acc);
            r[u] = acc;
        }
        union { bf16 b[4]; uint2 u2; } pk;
        pk.b[0] = f2b(r[0]); pk.b[1] = f2b(r[1]); pk.b[2] = f2b(r[2]); pk.b[3] = f2b(r[3]);
        *(uint2*)(dst + c0) = pk.u2;
    }
}

__global__ __launch_bounds__(256) void pre_ws_kernel(const void* r_ij,
        const float* __restrict__ WdT, const int* __restrict__ pos_of_e,
        bf16* __restrict__ ws_w, const int* __restrict__ flags, int nE) {
    int e = blockIdx.x * blockDim.x + threadIdx.x;
    if (e >= nE) return;
    if (flags[0]) pre_ws_body<1>(r_ij, WdT, pos_of_e, ws_w, e);
    else          pre_ws_body<0>(r_ij, WdT, pos_of_e, ws_w, e);
}

// ---------- mode A message: pure gather-accumulate ----------
template<int F32>
__device__ void msg_a_body(const bf16* __restrict__ ws_w, const bf16* __restrict__ phi,
        const void* __restrict__ v_j, const int* __restrict__ src_ids,
        const float4* __restrict__ u_env, const int* __restrict__ offsets,
        void* __restrict__ out, int nE, int nN) {
    const int i = blockIdx.x;
    const int f = threadIdx.x;
    int start = offsets[i];
    int end   = offsets[i + 1];
    if (start < 0) start = 0;
    if (end > nE) end = nE;

    float ds = 0.f, dv0 = 0.f, dv1 = 0.f, dv2 = 0.f;

    #pragma unroll 2
    for (int p = start; p < end; ++p) {
        const int j = src_ids[p];          // uniform -> s_load
        const float4 ue = u_env[p];        // uniform -> s_load
        const bf16* wr = ws_w + (size_t)p * 384;
        const float w0 = b2f(wr[f]);
        const float w1 = b2f(wr[FEAT + f]);
        const float w2 = b2f(wr[2 * FEAT + f]);
        const bf16* ph = phi + (size_t)j * 384;
        const float p0 = b2f(ph[f]);
        const float p1 = b2f(ph[FEAT + f]);
        const float p2 = b2f(ph[2 * FEAT + f]);
        const float vx = LD<F32>(v_j, ((size_t)j * FEAT + f) * 3 + 0);
        const float vy = LD<F32>(v_j, ((size_t)j * FEAT + f) * 3 + 1);
        const float vz = LD<F32>(v_j, ((size_t)j * FEAT + f) * 3 + 2);
        const float i0 = w0 * p0;
        const float i1 = w1 * p1;
        const float i2 = w2 * p2;
        ds += i1;
        dv0 = fmaf(i2, ue.x, fmaf(i0, vx, dv0));
        dv1 = fmaf(i2, ue.y, fmaf(i0, vy, dv1));
        dv2 = fmaf(i2, ue.z, fmaf(i0, vz, dv2));
    }

    ST<F32>(out, (size_t)i * FEAT + f, ds);
    const size_t ob = (size_t)nN * FEAT + ((size_t)i * FEAT + f) * 3;
    ST<F32>(out, ob + 0, dv0);
    ST<F32>(out, ob + 1, dv1);
    ST<F32>(out, ob + 2, dv2);
}

__global__ __launch_bounds__(128) void msg_a_kernel(const bf16* ws_w, const bf16* phi,
        const void* v_j, const int* src_ids, const float4* u_env, const int* offsets,
        const int* __restrict__ flags, void* out, int nE, int nN) {
    if (flags[0]) msg_a_body<1>(ws_w, phi, v_j, src_ids, u_env, offsets, out, nE, nN);
    else          msg_a_body<0>(ws_w, phi, v_j, src_ids, u_env, offsets, out, nE, nN);
}

// ---------- mode B message (fallback, round-4 style with sequential g) ----------
template<int F32>
__device__ void msg_b_body(const void* __restrict__ v_j, const void* __restrict__ Wd,
        const void* __restrict__ bd, const bf16* __restrict__ phi,
        const float* __restrict__ gbuf, const int* __restrict__ src_ids,
        const float4* __restrict__ u_env, const int* __restrict__ offsets,
        void* __restrict__ out, int nE, int nN) {
    const int i = blockIdx.x;
    const int f = threadIdx.x;

    float wd0[NRBF], wd1[NRBF], wd2[NRBF];
    #pragma unroll
    for (int k = 0; k < NRBF; ++k) {
        wd0[k] = LD<F32>(Wd, (size_t)k * 384 + f);
        wd1[k] = LD<F32>(Wd, (size_t)k * 384 + FEAT + f);
        wd2[k] = LD<F32>(Wd, (size_t)k * 384 + 2 * FEAT + f);
    }
    const float bd0 = LD<F32>(bd, f);
    const float bd1 = LD<F32>(bd, FEAT + f);
    const float bd2 = LD<F32>(bd, 2 * FEAT + f);

    int start = offsets[i];
    int end   = offsets[i + 1];
    if (start < 0) start = 0;
    if (end > nE) end = nE;

    float ds = 0.f, dv0 = 0.f, dv1 = 0.f, dv2 = 0.f;

    for (int p = start; p < end; ++p) {
        const int j = src_ids[p];
        const float4 ue = u_env[p];
        const float* g = gbuf + (size_t)p * NRBF;
        float t0 = 0.f, t1 = 0.f, t2 = 0.f;
        #pragma unroll
        for (int k = 0; k < NRBF; ++k) {
            const float gk = g[k];
            t0 = fmaf(gk, wd0[k], t0);
            t1 = fmaf(gk, wd1[k], t1);
            t2 = fmaf(gk, wd2[k], t2);
        }
        const float w0 = fmaf(bd0, ue.w, t0);
        const float w1 = fmaf(bd1, ue.w, t1);
        const float w2 = fmaf(bd2, ue.w, t2);

        const bf16* ph = phi + (size_t)j * 384;
        const float p0 = b2f(ph[f]);
        const float p1 = b2f(ph[FEAT + f]);
        const float p2 = b2f(ph[2 * FEAT + f]);
        const float vx = LD<F32>(v_j, ((size_t)j * FEAT + f) * 3 + 0);
        const float vy = LD<F32>(v_j, ((size_t)j * FEAT + f) * 3 + 1);
        const float vz = LD<F32>(v_j, ((size_t)j * FEAT + f) * 3 + 2);

        const float i0 = w0 * p0;
        const float i1 = w1 * p1;
        const float i2 = w2 * p2;
        ds += i1;
        dv0 = fmaf(i2, ue.x, fmaf(i0, vx, dv0));
        dv1 = fmaf(i2, ue.y, fmaf(i0, vy, dv1));
        dv2 = fmaf(i2, ue.z, fmaf(i0, vz, dv2));
    }

    ST<F32>(out, (size_t)i * FEAT + f, ds);
    const size_t ob = (size_t)nN * FEAT + ((size_t)i * FEAT + f) * 3;
    ST<F32>(out, ob + 0, dv0);
    ST<F32>(out, ob + 1, dv1);
    ST<F32>(out, ob + 2, dv2);
}

__global__ __launch_bounds__(128) void msg_b_kernel(const void* v_j, const void* Wd,
        const void* bd, const bf16* phi, const float* gbuf, const int* src_ids,
        const float4* u_env, const int* offsets, const int* __restrict__ flags,
        void* out, int nE, int nN) {
    if (flags[0]) msg_b_body<1>(v_j, Wd, bd, phi, gbuf, src_ids, u_env, offsets, out, nE, nN);
    else          msg_b_body<0>(v_j, Wd, bd, phi, gbuf, src_ids, u_env, offsets, out, nE, nN);
}

extern "C" void kernel_launch(void* const* d_in, const int* in_sizes, int n_in,
                              void* d_out, int out_size, void* d_ws, size_t ws_size,
                              hipStream_t stream) {
    const void* s_j  = d_in[0];
    const void* v_j  = d_in[1];
    const void* r_ij = d_in[2];
    const int*  nbrs = (const int*)d_in[3];
    const void* W1   = d_in[4];
    const void* b1   = d_in[5];
    const void* W2   = d_in[6];
    const void* b2   = d_in[7];
    const void* Wd   = d_in[8];
    const void* bd   = d_in[9];

    const int nN = out_size / (4 * FEAT);   // 20000
    const int nE = in_sizes[2] / 3;         // 640000

    char* ws = (char*)d_ws;
    size_t off = 0;
    auto alloc = [&](size_t bytes) -> void* {
        void* p = ws + off;
        off = (off + bytes + 255) & ~(size_t)255;
        return p;
    };
    int*    flags    = (int*)alloc(16);
    int*    counts   = (int*)alloc((size_t)nN * 4);
    int*    offsets  = (int*)alloc(((size_t)nN + 1) * 4);
    int*    cursor   = (int*)alloc((size_t)nN * 4);
    int*    src_ids  = (int*)alloc((size_t)nE * 4);
    float4* u_env    = (float4*)alloc((size_t)nE * 16);
    float*  WdT      = (float*)alloc((size_t)384 * 24 * 4);
    const size_t base = off;

    // mode A layout: pos_of_e | phi | ws_w
    size_t offA = base;
    int*  pos_of_e = (int*)(ws + offA);  offA += ((size_t)nE * 4 + 255) & ~(size_t)255;
    bf16* phiA     = (bf16*)(ws + offA); offA += ((size_t)nN * 384 * 2 + 255) & ~(size_t)255;
    bf16* ws_w     = (bf16*)(ws + offA); offA += (size_t)nE * 384 * 2;
    // mode B layout: gbuf | phi
    size_t offB = base;
    float* gbuf = (float*)(ws + offB);   offB += ((size_t)nE * NRBF * 4 + 255) & ~(size_t)255;
    bf16*  phiB = (bf16*)(ws + offB);    offB += (size_t)nN * 384 * 2;

    const int modeA = (ws_size >= offA) ? 1 : 0;
    bf16* phi = modeA ? phiA : phiB;

    init_kernel<<<(nN + 255) / 256, 256, 0, stream>>>(s_j, nbrs, nE, flags, counts, nN);
    hist_kernel<<<(nE + 255) / 256, 256, 0, stream>>>(nbrs, flags, counts, nE, nN);
    scan_kernel<<<1, 1024, 0, stream>>>(counts, offsets, cursor, nN);
    prep_kernel<<<1, 384, 0, stream>>>(Wd, bd, WdT, flags);

    pre_scatter_kernel<<<(nE + 255) / 256, 256, 0, stream>>>(
        r_ij, nbrs, flags, cursor, src_ids, u_env, pos_of_e, gbuf, nE, nN, modeA);

    gemm_node_kernel<<<(nN + 7) / 8, 384, 0, stream>>>(s_j, W1, b1, W2, b2, phi, flags, nN);

    if (modeA) {
        pre_ws_kernel<<<(nE + 255) / 256, 256, 0, stream>>>(r_ij, WdT, pos_of_e, ws_w, flags, nE);
        msg_a_kernel<<<nN, 128, 0, stream>>>(ws_w, phi, v_j, src_ids, u_env, offsets,
                                             flags, d_out, nE, nN);
    } else {
        msg_b_kernel<<<nN, 128, 0, stream>>>(v_j, Wd, bd, phi, gbuf, src_ids, u_env,
                                             offsets, flags, d_out, nE, nN);
    }
}